// Round 3
// baseline (393.505 us; speedup 1.0000x reference)
//
#include <hip/hip_runtime.h>
#include <hip/hip_bf16.h>

#define N_NODES 10000
#define N_EDGES 320000
#define D 128
#define NBINS 10000

typedef float f32x4 __attribute__((ext_vector_type(4)));
typedef float f32x2 __attribute__((ext_vector_type(2)));
typedef short bf16x8 __attribute__((ext_vector_type(8)));

static __device__ inline short f2bf(float f) {
    union { __hip_bfloat16 h; short s; } u;
    u.h = __float2bfloat16(f);
    return u.s;
}

static __device__ inline float fast_rcp(float x) { return __builtin_amdgcn_rcpf(x); }

// Pack W (K x 128 f32 row-major; rows >=128 come from W1) into B-fragment order:
// out[((t*8+jt)*64+l)*8+b] = Wcat[32t + (l>>4)*8 + b][jt*16 + (l&15)]
__global__ void prepack_kernel(const float* __restrict__ W0, const float* __restrict__ W1,
                               short* __restrict__ out, int K) {
    int idx = blockIdx.x * 256 + threadIdx.x;
    if (idx >= K * 128) return;
    int b  = idx & 7;
    int l  = (idx >> 3) & 63;
    int jt = (idx >> 9) & 7;
    int t  = idx >> 12;
    int k = 32 * t + ((l >> 4) * 8) + b;
    int j = jt * 16 + (l & 15);
    float v = (k < 128) ? W0[k * 128 + j] : W1[(k - 128) * 128 + j];
    out[idx] = f2bf(v);
}

// ---- counting sort of edges by dst ----
__global__ void hist_kernel(const int* __restrict__ dst, int* __restrict__ cnt) {
    int i = blockIdx.x * 256 + threadIdx.x;
    if (i < N_EDGES) atomicAdd(&cnt[dst[i]], 1);
}

__launch_bounds__(1024)
__global__ void scan_kernel(const int* __restrict__ cnt, int* __restrict__ cursor,
                            int* __restrict__ row_start) {
    __shared__ int s[1024];
    int t = threadIdx.x;
    int b0 = t * 10;
    int loc[10];
    int tot = 0;
#pragma unroll
    for (int i = 0; i < 10; ++i) {
        int v = (b0 + i < NBINS) ? cnt[b0 + i] : 0;
        loc[i] = tot; tot += v;
    }
    s[t] = tot;
    __syncthreads();
    for (int off = 1; off < 1024; off <<= 1) {
        int v = (t >= off) ? s[t - off] : 0;
        __syncthreads();
        s[t] += v;
        __syncthreads();
    }
    int base = (t == 0) ? 0 : s[t - 1];
#pragma unroll
    for (int i = 0; i < 10; ++i)
        if (b0 + i < NBINS) {
            cursor[b0 + i] = base + loc[i];
            row_start[b0 + i] = base + loc[i];
        }
    if (t == 0) row_start[NBINS] = N_EDGES;
}

__global__ void scatter_kernel(const int* __restrict__ dst, int* __restrict__ cursor,
                               int* __restrict__ perm) {
    int i = blockIdx.x * 256 + threadIdx.x;
    if (i < N_EDGES) {
        int p = atomicAdd(&cursor[dst[i]], 1);
        perm[p] = i;
    }
}

__launch_bounds__(256)
__global__ void node_proj_kernel(const float* __restrict__ node,
                                 const float* __restrict__ timef,
                                 const short* __restrict__ Wsrc_pk,  // K=256 (W_sg ; W_tp)
                                 const short* __restrict__ Wdg_pk,
                                 const short* __restrict__ Wdu_pk,
                                 const short* __restrict__ Wsu_pk,
                                 const float* __restrict__ b_sg, const float* __restrict__ b_tp,
                                 const float* __restrict__ b_dg, const float* __restrict__ b_du,
                                 const float* __restrict__ b_su, const float* __restrict__ b_eg,
                                 float* __restrict__ e_src, float* __restrict__ e_dst,
                                 float* __restrict__ Bh, float* __restrict__ xs) {
    int tid = threadIdx.x;
    int w = tid >> 6;
    int l = tid & 63;
    int g = l >> 4;
    int lr = l & 15;
    int r0 = blockIdx.x * 64 + w * 16;
    int arow = r0 + lr;

    bf16x8 aN[4], aT[4];
    if (arow < N_NODES) {
        const float* np = node + (size_t)arow * D;
        const float* tp = timef + (size_t)arow * D;
#pragma unroll
        for (int t = 0; t < 4; ++t) {
            int k0 = 32 * t + g * 8;
            f32x4 v0 = *(const f32x4*)(np + k0);
            f32x4 v1 = *(const f32x4*)(np + k0 + 4);
            f32x4 u0 = *(const f32x4*)(tp + k0);
            f32x4 u1 = *(const f32x4*)(tp + k0 + 4);
            bf16x8 a, b;
#pragma unroll
            for (int i = 0; i < 4; ++i) {
                a[i] = f2bf(v0[i]); a[4 + i] = f2bf(v1[i]);
                b[i] = f2bf(u0[i]); b[4 + i] = f2bf(u1[i]);
            }
            aN[t] = a; aT[t] = b;
        }
    } else {
        bf16x8 z = {0, 0, 0, 0, 0, 0, 0, 0};
#pragma unroll
        for (int t = 0; t < 4; ++t) { aN[t] = z; aT[t] = z; }
    }

    const bf16x8* Bsrc = (const bf16x8*)Wsrc_pk;
    const bf16x8* Bdg  = (const bf16x8*)Wdg_pk;
    const bf16x8* Bdu  = (const bf16x8*)Wdu_pk;
    const bf16x8* Bsu  = (const bf16x8*)Wsu_pk;

    // e_src = node@W_sg + time@W_tp + b_sg + b_tp   (K = 256)
#pragma unroll
    for (int jt = 0; jt < 8; ++jt) {
        int c = jt * 16 + lr;
        f32x4 acc = {0.f, 0.f, 0.f, 0.f};
#pragma unroll
        for (int t = 0; t < 4; ++t)
            acc = __builtin_amdgcn_mfma_f32_16x16x32_bf16(aN[t], Bsrc[(t * 8 + jt) * 64 + l], acc, 0, 0, 0);
#pragma unroll
        for (int t = 0; t < 4; ++t)
            acc = __builtin_amdgcn_mfma_f32_16x16x32_bf16(aT[t], Bsrc[((4 + t) * 8 + jt) * 64 + l], acc, 0, 0, 0);
        float bias = b_sg[c] + b_tp[c];
#pragma unroll
        for (int r = 0; r < 4; ++r) {
            int row = r0 + g * 4 + r;
            if (row < N_NODES) e_src[(size_t)row * D + c] = acc[r] + bias;
        }
    }

    // e_dst (+b_eg folded), Bh, xs   (K = 128 from node)
#pragma unroll
    for (int jt = 0; jt < 8; ++jt) {
        int c = jt * 16 + lr;
        f32x4 a0 = {0.f, 0.f, 0.f, 0.f}, a1 = a0, a2 = a0;
#pragma unroll
        for (int t = 0; t < 4; ++t) {
            a0 = __builtin_amdgcn_mfma_f32_16x16x32_bf16(aN[t], Bdg[(t * 8 + jt) * 64 + l], a0, 0, 0, 0);
            a1 = __builtin_amdgcn_mfma_f32_16x16x32_bf16(aN[t], Bdu[(t * 8 + jt) * 64 + l], a1, 0, 0, 0);
            a2 = __builtin_amdgcn_mfma_f32_16x16x32_bf16(aN[t], Bsu[(t * 8 + jt) * 64 + l], a2, 0, 0, 0);
        }
        float bdgc = b_dg[c] + b_eg[c];
        float bdu = b_du[c], bsu = b_su[c];
#pragma unroll
        for (int r = 0; r < 4; ++r) {
            int row = r0 + g * 4 + r;
            if (row < N_NODES) {
                e_dst[(size_t)row * D + c] = a0[r] + bdgc;
                Bh[(size_t)row * D + c]    = a1[r] + bdu;
                xs[(size_t)row * D + c]    = a2[r] + bsu;
            }
        }
    }
}

// One wave per dst node: processes the node's dst-sorted edge run in 16-edge
// MFMA tiles. ss/ssh accumulate in registers (no atomics); node epilogue
// (h, LayerNorm, SiLU, residual) fused at run end.
__launch_bounds__(256)
__global__ void edge_node_kernel(const float* __restrict__ edgef,
                                 const int* __restrict__ src,
                                 const int* __restrict__ perm,
                                 const int* __restrict__ row_start,
                                 const short* __restrict__ Weg_pk,
                                 const float* __restrict__ e_src,
                                 const float* __restrict__ e_dstb,  // includes b_eg
                                 const float* __restrict__ Bh,
                                 const float* __restrict__ ln_e_g, const float* __restrict__ ln_e_b,
                                 const float* __restrict__ node,
                                 const float* __restrict__ xs,
                                 const float* __restrict__ ln_n_g, const float* __restrict__ ln_n_b,
                                 float* __restrict__ x, float* __restrict__ y) {
    const int tid = threadIdx.x;
    const int l = tid & 63;
    const int g = l >> 4;
    const int lr = l & 15;
    const int d = blockIdx.x * 4 + (tid >> 6);
    if (d >= N_NODES) return;
    const int p0 = row_start[d], p1 = row_start[d + 1];

    float edst[8], gcol[8], bbcol[8];
#pragma unroll
    for (int jt = 0; jt < 8; ++jt) {
        int c = jt * 16 + lr;
        edst[jt] = e_dstb[(size_t)d * D + c];
        gcol[jt] = ln_e_g[c];
        bbcol[jt] = ln_e_b[c];
    }
    float ssS[8], ssH[8];
#pragma unroll
    for (int jt = 0; jt < 8; ++jt) { ssS[jt] = 0.f; ssH[jt] = 0.f; }

    const bf16x8* Bp = (const bf16x8*)Weg_pk;

    for (int p = p0; p < p1; p += 16) {
        const int nval = p1 - p;                  // >= 1
        const int ar = (lr < nval) ? lr : (nval - 1);
        const int eA = perm[p + ar];
        int eidx[4], sidx[4];
        bool val[4];
#pragma unroll
        for (int r = 0; r < 4; ++r) {
            int qq = g * 4 + r;
            val[r] = qq < nval;
            eidx[r] = perm[p + (val[r] ? qq : 0)];
            sidx[r] = src[eidx[r]];
        }

        // A fragments: 16 edges x 128 k, bf16
        bf16x8 aE[4];
        {
            const float* ep = edgef + (size_t)eA * D;
#pragma unroll
            for (int t = 0; t < 4; ++t) {
                int k0 = 32 * t + g * 8;
                f32x4 v0 = *(const f32x4*)(ep + k0);
                f32x4 v1 = *(const f32x4*)(ep + k0 + 4);
                bf16x8 a;
#pragma unroll
                for (int i = 0; i < 4; ++i) { a[i] = f2bf(v0[i]); a[4 + i] = f2bf(v1[i]); }
                aE[t] = a;
            }
        }

        f32x4 acc[8];
#pragma unroll
        for (int jt = 0; jt < 8; ++jt) {
            f32x4 c4 = {0.f, 0.f, 0.f, 0.f};
#pragma unroll
            for (int t = 0; t < 4; ++t)
                c4 = __builtin_amdgcn_mfma_f32_16x16x32_bf16(aE[t], Bp[(t * 8 + jt) * 64 + l], c4, 0, 0, 0);
            acc[jt] = c4;
        }

        float sum[4] = {0.f, 0.f, 0.f, 0.f}, sq[4] = {0.f, 0.f, 0.f, 0.f};
#pragma unroll
        for (int jt = 0; jt < 8; ++jt) {
            int c = jt * 16 + lr;
#pragma unroll
            for (int r = 0; r < 4; ++r) {
                float m = acc[jt][r] + e_src[(size_t)sidx[r] * D + c] + edst[jt];
                acc[jt][r] = m;  // keep for LN pass
                float s = val[r] ? fast_rcp(1.f + __expf(-m)) : 0.f;
                ssS[jt] += s;
                ssH[jt] += Bh[(size_t)sidx[r] * D + c] * s;
                sum[r] += m; sq[r] += m * m;
            }
        }

        // per-edge LayerNorm stats: reduce over the 16 lanes sharing l>>4
#pragma unroll
        for (int r = 0; r < 4; ++r) {
            float s = sum[r], q = sq[r];
#pragma unroll
            for (int mk = 1; mk < 16; mk <<= 1) { s += __shfl_xor(s, mk); q += __shfl_xor(q, mk); }
            float mean = s * (1.f / D);
            float var = q * (1.f / D) - mean * mean;
            sum[r] = mean;
            sq[r] = rsqrtf(var + 1e-5f);
        }

#pragma unroll
        for (int jt = 0; jt < 8; ++jt) {
            int c = jt * 16 + lr;
#pragma unroll
            for (int r = 0; r < 4; ++r) {
                if (val[r]) {
                    float v = (acc[jt][r] - sum[r]) * sq[r] * gcol[jt] + bbcol[jt];
                    float sl = v * fast_rcp(1.f + __expf(-v));
                    size_t off = (size_t)eidx[r] * D + c;
                    y[off] = edgef[off] + sl;
                }
            }
        }
    }

    // ---- node epilogue: h = ssh/(ss+eps); x = node + silu(LN(xs + h)) ----
#pragma unroll
    for (int jt = 0; jt < 8; ++jt) {
        float a = ssS[jt], b = ssH[jt];
        a += __shfl_xor(a, 16); b += __shfl_xor(b, 16);
        a += __shfl_xor(a, 32); b += __shfl_xor(b, 32);
        ssS[jt] = a; ssH[jt] = b;
    }
    float v[8];
    float s = 0.f, q = 0.f;
#pragma unroll
    for (int jt = 0; jt < 8; ++jt) {
        int c = jt * 16 + lr;
        float h = ssH[jt] / (ssS[jt] + 1e-6f);
        float xv = xs[(size_t)d * D + c] + h;
        v[jt] = xv; s += xv; q += xv * xv;
    }
#pragma unroll
    for (int mk = 1; mk < 16; mk <<= 1) { s += __shfl_xor(s, mk); q += __shfl_xor(q, mk); }
    float mean = s * (1.f / D);
    float rstd = rsqrtf(q * (1.f / D) - mean * mean + 1e-5f);
    if (g == 0) {
#pragma unroll
        for (int jt = 0; jt < 8; ++jt) {
            int c = jt * 16 + lr;
            float t = (v[jt] - mean) * rstd * ln_n_g[c] + ln_n_b[c];
            t = t * fast_rcp(1.f + __expf(-t));
            x[(size_t)d * D + c] = node[(size_t)d * D + c] + t;
        }
    }
}

extern "C" void kernel_launch(void* const* d_in, const int* in_sizes, int n_in,
                              void* d_out, int out_size, void* d_ws, size_t ws_size,
                              hipStream_t stream) {
    const float* node  = (const float*)d_in[0];
    const float* edgef = (const float*)d_in[1];
    const float* timef = (const float*)d_in[2];
    const int*   src   = (const int*)d_in[3];
    const int*   dst   = (const int*)d_in[4];
    const float* W_tp = (const float*)d_in[5];  const float* b_tp = (const float*)d_in[6];
    const float* W_sg = (const float*)d_in[7];  const float* b_sg = (const float*)d_in[8];
    const float* W_dg = (const float*)d_in[9];  const float* b_dg = (const float*)d_in[10];
    const float* W_eg = (const float*)d_in[11]; const float* b_eg = (const float*)d_in[12];
    const float* W_su = (const float*)d_in[13]; const float* b_su = (const float*)d_in[14];
    const float* W_du = (const float*)d_in[15]; const float* b_du = (const float*)d_in[16];
    const float* ln_e_g = (const float*)d_in[17]; const float* ln_e_b = (const float*)d_in[18];
    const float* ln_n_g = (const float*)d_in[19]; const float* ln_n_b = (const float*)d_in[20];

    char* ws = (char*)d_ws;
    size_t nd = (size_t)N_NODES * D;
    float* e_src = (float*)ws; ws += nd * 4;
    float* e_dst = (float*)ws; ws += nd * 4;
    float* Bh    = (float*)ws; ws += nd * 4;
    float* xs    = (float*)ws; ws += nd * 4;
    short* Wsrc_pk = (short*)ws; ws += 256 * 128 * 2;
    short* Wdg_pk  = (short*)ws; ws += 128 * 128 * 2;
    short* Wdu_pk  = (short*)ws; ws += 128 * 128 * 2;
    short* Wsu_pk  = (short*)ws; ws += 128 * 128 * 2;
    short* Weg_pk  = (short*)ws; ws += 128 * 128 * 2;
    int* cnt       = (int*)ws; ws += 10240 * 4;
    int* cursor    = (int*)ws; ws += 10240 * 4;
    int* row_start = (int*)ws; ws += 10240 * 4;
    int* perm      = (int*)ws; ws += (size_t)N_EDGES * 4;

    // zero the histogram (cursor/row_start are fully written by scan)
    hipMemsetAsync(cnt, 0, 10240 * 4, stream);

    // build dst-sorted edge permutation + CSR row offsets
    hist_kernel<<<(N_EDGES + 255) / 256, 256, 0, stream>>>(dst, cnt);
    scan_kernel<<<1, 1024, 0, stream>>>(cnt, cursor, row_start);
    scatter_kernel<<<(N_EDGES + 255) / 256, 256, 0, stream>>>(dst, cursor, perm);

    prepack_kernel<<<128, 256, 0, stream>>>(W_sg, W_tp, Wsrc_pk, 256);
    prepack_kernel<<<64, 256, 0, stream>>>(W_dg, W_dg, Wdg_pk, 128);
    prepack_kernel<<<64, 256, 0, stream>>>(W_du, W_du, Wdu_pk, 128);
    prepack_kernel<<<64, 256, 0, stream>>>(W_su, W_su, Wsu_pk, 128);
    prepack_kernel<<<64, 256, 0, stream>>>(W_eg, W_eg, Weg_pk, 128);

    node_proj_kernel<<<(N_NODES + 63) / 64, 256, 0, stream>>>(
        node, timef, Wsrc_pk, Wdg_pk, Wdu_pk, Wsu_pk,
        b_sg, b_tp, b_dg, b_du, b_su, b_eg, e_src, e_dst, Bh, xs);

    edge_node_kernel<<<(N_NODES + 3) / 4, 256, 0, stream>>>(
        edgef, src, perm, row_start, Weg_pk, e_src, e_dst, Bh,
        ln_e_g, ln_e_b, node, xs, ln_n_g, ln_n_b,
        (float*)d_out, (float*)d_out + nd);
}

// Round 4
// 290.988 us; speedup vs baseline: 1.3523x; 1.3523x over previous
//
#include <hip/hip_runtime.h>
#include <hip/hip_bf16.h>

#define N_NODES 10000
#define N_EDGES 320000
#define D 128
#define NBINS 10000

typedef float f32x4 __attribute__((ext_vector_type(4)));
typedef float f32x2 __attribute__((ext_vector_type(2)));
typedef short bf16x8 __attribute__((ext_vector_type(8)));

static __device__ inline short f2bf(float f) {
    union { __hip_bfloat16 h; short s; } u;
    u.h = __float2bfloat16(f);
    return u.s;
}

static __device__ inline float bf2f(short s) {
    union { float f; unsigned u; } x;
    x.u = ((unsigned)(unsigned short)s) << 16;
    return x.f;
}

static __device__ inline float fast_rcp(float x) { return __builtin_amdgcn_rcpf(x); }

// Pack W (K x 128 f32 row-major; rows >=128 come from W1) into B-fragment order:
// out[((t*8+jt)*64+l)*8+b] = Wcat[32t + (l>>4)*8 + b][jt*16 + (l&15)]
__global__ void prepack_kernel(const float* __restrict__ W0, const float* __restrict__ W1,
                               short* __restrict__ out, int K) {
    int idx = blockIdx.x * 256 + threadIdx.x;
    if (idx >= K * 128) return;
    int b  = idx & 7;
    int l  = (idx >> 3) & 63;
    int jt = (idx >> 9) & 7;
    int t  = idx >> 12;
    int k = 32 * t + ((l >> 4) * 8) + b;
    int j = jt * 16 + (l & 15);
    float v = (k < 128) ? W0[k * 128 + j] : W1[(k - 128) * 128 + j];
    out[idx] = f2bf(v);
}

// ---- counting sort of edges by dst ----
__global__ void hist_kernel(const int* __restrict__ dst, int* __restrict__ cnt) {
    int i = blockIdx.x * 256 + threadIdx.x;
    if (i < N_EDGES) atomicAdd(&cnt[dst[i]], 1);
}

__launch_bounds__(1024)
__global__ void scan_kernel(const int* __restrict__ cnt, int* __restrict__ cursor) {
    __shared__ int s[1024];
    int t = threadIdx.x;
    int b0 = t * 10;
    int loc[10];
    int tot = 0;
#pragma unroll
    for (int i = 0; i < 10; ++i) {
        int v = (b0 + i < NBINS) ? cnt[b0 + i] : 0;
        loc[i] = tot; tot += v;
    }
    s[t] = tot;
    __syncthreads();
    for (int off = 1; off < 1024; off <<= 1) {
        int v = (t >= off) ? s[t - off] : 0;
        __syncthreads();
        s[t] += v;
        __syncthreads();
    }
    int base = (t == 0) ? 0 : s[t - 1];
#pragma unroll
    for (int i = 0; i < 10; ++i)
        if (b0 + i < NBINS) cursor[b0 + i] = base + loc[i];
}

__global__ void scatter_kernel(const int* __restrict__ dst, int* __restrict__ cursor,
                               int* __restrict__ perm) {
    int i = blockIdx.x * 256 + threadIdx.x;
    if (i < N_EDGES) {
        int p = atomicAdd(&cursor[dst[i]], 1);
        perm[p] = i;
    }
}

__launch_bounds__(256)
__global__ void node_proj_kernel(const float* __restrict__ node,
                                 const float* __restrict__ timef,
                                 const short* __restrict__ Wsrc_pk,  // K=256 (W_sg ; W_tp)
                                 const short* __restrict__ Wdg_pk,
                                 const short* __restrict__ Wdu_pk,
                                 const short* __restrict__ Wsu_pk,
                                 const float* __restrict__ b_sg, const float* __restrict__ b_tp,
                                 const float* __restrict__ b_dg, const float* __restrict__ b_du,
                                 const float* __restrict__ b_su, const float* __restrict__ b_eg,
                                 short* __restrict__ spk,   // [N][256] bf16: e_src | Bh
                                 short* __restrict__ dpk,   // [N][128] bf16: e_dst (+b_dg+b_eg)
                                 float* __restrict__ xs) {
    int tid = threadIdx.x;
    int w = tid >> 6;
    int l = tid & 63;
    int g = l >> 4;
    int lr = l & 15;
    int r0 = blockIdx.x * 64 + w * 16;
    int arow = r0 + lr;

    bf16x8 aN[4], aT[4];
    if (arow < N_NODES) {
        const float* np = node + (size_t)arow * D;
        const float* tp = timef + (size_t)arow * D;
#pragma unroll
        for (int t = 0; t < 4; ++t) {
            int k0 = 32 * t + g * 8;
            f32x4 v0 = *(const f32x4*)(np + k0);
            f32x4 v1 = *(const f32x4*)(np + k0 + 4);
            f32x4 u0 = *(const f32x4*)(tp + k0);
            f32x4 u1 = *(const f32x4*)(tp + k0 + 4);
            bf16x8 a, b;
#pragma unroll
            for (int i = 0; i < 4; ++i) {
                a[i] = f2bf(v0[i]); a[4 + i] = f2bf(v1[i]);
                b[i] = f2bf(u0[i]); b[4 + i] = f2bf(u1[i]);
            }
            aN[t] = a; aT[t] = b;
        }
    } else {
        bf16x8 z = {0, 0, 0, 0, 0, 0, 0, 0};
#pragma unroll
        for (int t = 0; t < 4; ++t) { aN[t] = z; aT[t] = z; }
    }

    const bf16x8* Bsrc = (const bf16x8*)Wsrc_pk;
    const bf16x8* Bdg  = (const bf16x8*)Wdg_pk;
    const bf16x8* Bdu  = (const bf16x8*)Wdu_pk;
    const bf16x8* Bsu  = (const bf16x8*)Wsu_pk;

    // e_src = node@W_sg + time@W_tp + b_sg + b_tp   (K = 256)
#pragma unroll
    for (int jt = 0; jt < 8; ++jt) {
        int c = jt * 16 + lr;
        f32x4 acc = {0.f, 0.f, 0.f, 0.f};
#pragma unroll
        for (int t = 0; t < 4; ++t)
            acc = __builtin_amdgcn_mfma_f32_16x16x32_bf16(aN[t], Bsrc[(t * 8 + jt) * 64 + l], acc, 0, 0, 0);
#pragma unroll
        for (int t = 0; t < 4; ++t)
            acc = __builtin_amdgcn_mfma_f32_16x16x32_bf16(aT[t], Bsrc[((4 + t) * 8 + jt) * 64 + l], acc, 0, 0, 0);
        float bias = b_sg[c] + b_tp[c];
#pragma unroll
        for (int r = 0; r < 4; ++r) {
            int row = r0 + g * 4 + r;
            if (row < N_NODES) spk[(size_t)row * 256 + c] = f2bf(acc[r] + bias);
        }
    }

    // e_dst (+b_dg+b_eg), Bh (+b_du), xs (+b_su)   (K = 128 from node)
#pragma unroll
    for (int jt = 0; jt < 8; ++jt) {
        int c = jt * 16 + lr;
        f32x4 a0 = {0.f, 0.f, 0.f, 0.f}, a1 = a0, a2 = a0;
#pragma unroll
        for (int t = 0; t < 4; ++t) {
            a0 = __builtin_amdgcn_mfma_f32_16x16x32_bf16(aN[t], Bdg[(t * 8 + jt) * 64 + l], a0, 0, 0, 0);
            a1 = __builtin_amdgcn_mfma_f32_16x16x32_bf16(aN[t], Bdu[(t * 8 + jt) * 64 + l], a1, 0, 0, 0);
            a2 = __builtin_amdgcn_mfma_f32_16x16x32_bf16(aN[t], Bsu[(t * 8 + jt) * 64 + l], a2, 0, 0, 0);
        }
        float bdgc = b_dg[c] + b_eg[c];
        float bdu = b_du[c], bsu = b_su[c];
#pragma unroll
        for (int r = 0; r < 4; ++r) {
            int row = r0 + g * 4 + r;
            if (row < N_NODES) {
                dpk[(size_t)row * D + c]       = f2bf(a0[r] + bdgc);
                spk[(size_t)row * 256 + 128 + c] = f2bf(a1[r] + bdu);
                xs[(size_t)row * D + c]        = a2[r] + bsu;
            }
        }
    }
}

// One 16-edge tile per wave, edges in dst-sorted (perm) order. Weg staged in LDS.
__launch_bounds__(256)
__global__ void edge_kernel(const float* __restrict__ edgef,
                            const int* __restrict__ src, const int* __restrict__ dst,
                            const int* __restrict__ perm,
                            const short* __restrict__ Weg_pk,
                            const short* __restrict__ spk,   // [N][256]: e_src | Bh
                            const short* __restrict__ dpk,   // [N][128]: e_dst
                            const float* __restrict__ ln_g, const float* __restrict__ ln_b,
                            float* __restrict__ ss, float* __restrict__ ssh,
                            float* __restrict__ y) {
    __shared__ short Bs[128 * 128];  // 32 KB: Weg B-fragments
    {
        const bf16x8* gw = (const bf16x8*)Weg_pk;
        bf16x8* sw = (bf16x8*)Bs;
        for (int i = threadIdx.x; i < 2048; i += 256) sw[i] = gw[i];
    }
    __syncthreads();

    int tid = threadIdx.x;
    int w = tid >> 6;
    int l = tid & 63;
    int g = l >> 4;
    int lr = l & 15;
    // XCD-chunked bijective swizzle (5000 % 8 == 0): consecutive dst-runs on one XCD
    int b = blockIdx.x;
    int swz = (b & 7) * 625 + (b >> 3);
    int e0 = swz * 64 + w * 16;

    int eA = perm[e0 + lr];          // A-fragment row (edge) for this lane
    int eidx[4], sidx[4], didx[4];
#pragma unroll
    for (int r = 0; r < 4; ++r) {
        eidx[r] = perm[e0 + g * 4 + r];
        sidx[r] = src[eidx[r]];
        didx[r] = dst[eidx[r]];
    }

    // A fragments: 16 edges x 128 k, bf16
    bf16x8 aE[4];
    {
        const float* ep = edgef + (size_t)eA * D;
#pragma unroll
        for (int t = 0; t < 4; ++t) {
            int k0 = 32 * t + g * 8;
            f32x4 v0 = *(const f32x4*)(ep + k0);
            f32x4 v1 = *(const f32x4*)(ep + k0 + 4);
            bf16x8 a;
#pragma unroll
            for (int i = 0; i < 4; ++i) { a[i] = f2bf(v0[i]); a[4 + i] = f2bf(v1[i]); }
            aE[t] = a;
        }
    }

    const bf16x8* Bp = (const bf16x8*)Bs;
    f32x4 acc[8];
#pragma unroll
    for (int jt = 0; jt < 8; ++jt) {
        f32x4 c4 = {0.f, 0.f, 0.f, 0.f};
#pragma unroll
        for (int t = 0; t < 4; ++t)
            c4 = __builtin_amdgcn_mfma_f32_16x16x32_bf16(aE[t], Bp[(t * 8 + jt) * 64 + l], c4, 0, 0, 0);
        acc[jt] = c4;
    }

    // sorted => tile uniform iff first and last edge share dst
    int dfirst = __shfl(didx[0], 0);
    int dlast  = __shfl(didx[3], 48);
    bool uniform = (dfirst == dlast);

    float gcol[8], bbcol[8];
#pragma unroll
    for (int jt = 0; jt < 8; ++jt) {
        int c = jt * 16 + lr;
        gcol[jt] = ln_g[c]; bbcol[jt] = ln_b[c];
    }

    float sum[4] = {0.f, 0.f, 0.f, 0.f}, sq[4] = {0.f, 0.f, 0.f, 0.f};
#pragma unroll
    for (int jt = 0; jt < 8; ++jt) {
        int c = jt * 16 + lr;
        float sg[4], bsg[4];
#pragma unroll
        for (int r = 0; r < 4; ++r) {
            float es = bf2f(spk[(size_t)sidx[r] * 256 + c]);
            float bh = bf2f(spk[(size_t)sidx[r] * 256 + 128 + c]);
            float ed = bf2f(dpk[(size_t)didx[r] * D + c]);
            float m = acc[jt][r] + es + ed;
            acc[jt][r] = m;  // keep for LN pass
            float s = fast_rcp(1.f + __expf(-m));
            sg[r] = s;
            bsg[r] = bh * s;
            sum[r] += m; sq[r] += m * m;
        }
        if (uniform) {
            float aS = (sg[0] + sg[1]) + (sg[2] + sg[3]);
            float aH = (bsg[0] + bsg[1]) + (bsg[2] + bsg[3]);
            aS += __shfl_xor(aS, 16); aH += __shfl_xor(aH, 16);
            aS += __shfl_xor(aS, 32); aH += __shfl_xor(aH, 32);
            if (g == 0) {
                atomicAdd(&ss [(size_t)dfirst * D + c], aS);
                atomicAdd(&ssh[(size_t)dfirst * D + c], aH);
            }
        } else {
            float aS = sg[0], aH = bsg[0];
#pragma unroll
            for (int r = 1; r < 4; ++r) {
                if (didx[r] == didx[r - 1]) { aS += sg[r]; aH += bsg[r]; }
                else {
                    atomicAdd(&ss [(size_t)didx[r - 1] * D + c], aS);
                    atomicAdd(&ssh[(size_t)didx[r - 1] * D + c], aH);
                    aS = sg[r]; aH = bsg[r];
                }
            }
            atomicAdd(&ss [(size_t)didx[3] * D + c], aS);
            atomicAdd(&ssh[(size_t)didx[3] * D + c], aH);
        }
    }

    // LayerNorm stats per edge: reduce over the 16 lanes sharing l>>4
#pragma unroll
    for (int r = 0; r < 4; ++r) {
        float s = sum[r], q = sq[r];
#pragma unroll
        for (int mk = 1; mk < 16; mk <<= 1) { s += __shfl_xor(s, mk); q += __shfl_xor(q, mk); }
        float mean = s * (1.f / D);
        float var = q * (1.f / D) - mean * mean;
        sum[r] = mean;
        sq[r] = rsqrtf(var + 1e-5f);
    }

#pragma unroll
    for (int jt = 0; jt < 8; ++jt) {
        int c = jt * 16 + lr;
#pragma unroll
        for (int r = 0; r < 4; ++r) {
            float v = (acc[jt][r] - sum[r]) * sq[r] * gcol[jt] + bbcol[jt];
            float sl = v * fast_rcp(1.f + __expf(-v));
            size_t off = (size_t)eidx[r] * D + c;
            y[off] = edgef[off] + sl;
        }
    }
}

__launch_bounds__(256)
__global__ void node_out_kernel(const float* __restrict__ node,
                                const float* __restrict__ xs,
                                const float* __restrict__ ssh, const float* __restrict__ ss,
                                const float* __restrict__ ln_g, const float* __restrict__ ln_b,
                                float* __restrict__ x) {
    int w = threadIdx.x >> 6;
    int l = threadIdx.x & 63;
    int row = blockIdx.x * 4 + w;
    if (row >= N_NODES) return;
    size_t base = (size_t)row * D + 2 * l;
    f32x2 xv = *(const f32x2*)(xs + base);
    f32x2 hs = *(const f32x2*)(ssh + base);
    f32x2 sv = *(const f32x2*)(ss + base);
    float v0 = xv[0] + hs[0] / (sv[0] + 1e-6f);
    float v1 = xv[1] + hs[1] / (sv[1] + 1e-6f);
    float s = v0 + v1, q = v0 * v0 + v1 * v1;
#pragma unroll
    for (int mk = 1; mk < 64; mk <<= 1) { s += __shfl_xor(s, mk); q += __shfl_xor(q, mk); }
    float mean = s * (1.f / D);
    float var = q * (1.f / D) - mean * mean;
    float rstd = rsqrtf(var + 1e-5f);
    float t0 = (v0 - mean) * rstd * ln_g[2 * l] + ln_b[2 * l];
    float t1 = (v1 - mean) * rstd * ln_g[2 * l + 1] + ln_b[2 * l + 1];
    t0 = t0 * fast_rcp(1.f + __expf(-t0));
    t1 = t1 * fast_rcp(1.f + __expf(-t1));
    f32x2 nv = *(const f32x2*)(node + base);
    f32x2 outv;
    outv[0] = nv[0] + t0;
    outv[1] = nv[1] + t1;
    *(f32x2*)(x + base) = outv;
}

extern "C" void kernel_launch(void* const* d_in, const int* in_sizes, int n_in,
                              void* d_out, int out_size, void* d_ws, size_t ws_size,
                              hipStream_t stream) {
    const float* node  = (const float*)d_in[0];
    const float* edgef = (const float*)d_in[1];
    const float* timef = (const float*)d_in[2];
    const int*   src   = (const int*)d_in[3];
    const int*   dst   = (const int*)d_in[4];
    const float* W_tp = (const float*)d_in[5];  const float* b_tp = (const float*)d_in[6];
    const float* W_sg = (const float*)d_in[7];  const float* b_sg = (const float*)d_in[8];
    const float* W_dg = (const float*)d_in[9];  const float* b_dg = (const float*)d_in[10];
    const float* W_eg = (const float*)d_in[11]; const float* b_eg = (const float*)d_in[12];
    const float* W_su = (const float*)d_in[13]; const float* b_su = (const float*)d_in[14];
    const float* W_du = (const float*)d_in[15]; const float* b_du = (const float*)d_in[16];
    const float* ln_e_g = (const float*)d_in[17]; const float* ln_e_b = (const float*)d_in[18];
    const float* ln_n_g = (const float*)d_in[19]; const float* ln_n_b = (const float*)d_in[20];

    char* ws = (char*)d_ws;
    size_t nd = (size_t)N_NODES * D;
    float* ss    = (float*)ws; ws += nd * 4;
    float* ssh   = (float*)ws; ws += nd * 4;
    float* xs    = (float*)ws; ws += nd * 4;
    short* spk   = (short*)ws; ws += (size_t)N_NODES * 256 * 2;
    short* dpk   = (short*)ws; ws += nd * 2;
    short* Wsrc_pk = (short*)ws; ws += 256 * 128 * 2;
    short* Wdg_pk  = (short*)ws; ws += 128 * 128 * 2;
    short* Wdu_pk  = (short*)ws; ws += 128 * 128 * 2;
    short* Wsu_pk  = (short*)ws; ws += 128 * 128 * 2;
    short* Weg_pk  = (short*)ws; ws += 128 * 128 * 2;
    int* cnt       = (int*)ws; ws += 10240 * 4;
    int* cursor    = (int*)ws; ws += 10240 * 4;
    int* perm      = (int*)ws; ws += (size_t)N_EDGES * 4;

    // zero accumulators (ss & ssh contiguous) and histogram
    hipMemsetAsync(ss, 0, 2 * nd * 4, stream);
    hipMemsetAsync(cnt, 0, 10240 * 4, stream);

    // build dst-sorted edge permutation
    hist_kernel<<<(N_EDGES + 255) / 256, 256, 0, stream>>>(dst, cnt);
    scan_kernel<<<1, 1024, 0, stream>>>(cnt, cursor);
    scatter_kernel<<<(N_EDGES + 255) / 256, 256, 0, stream>>>(dst, cursor, perm);

    prepack_kernel<<<128, 256, 0, stream>>>(W_sg, W_tp, Wsrc_pk, 256);
    prepack_kernel<<<64, 256, 0, stream>>>(W_dg, W_dg, Wdg_pk, 128);
    prepack_kernel<<<64, 256, 0, stream>>>(W_du, W_du, Wdu_pk, 128);
    prepack_kernel<<<64, 256, 0, stream>>>(W_su, W_su, Wsu_pk, 128);
    prepack_kernel<<<64, 256, 0, stream>>>(W_eg, W_eg, Weg_pk, 128);

    node_proj_kernel<<<(N_NODES + 63) / 64, 256, 0, stream>>>(
        node, timef, Wsrc_pk, Wdg_pk, Wdu_pk, Wsu_pk,
        b_sg, b_tp, b_dg, b_du, b_su, b_eg, spk, dpk, xs);

    edge_kernel<<<N_EDGES / 64, 256, 0, stream>>>(
        edgef, src, dst, perm, Weg_pk, spk, dpk,
        ln_e_g, ln_e_b, ss, ssh, (float*)d_out + nd);

    node_out_kernel<<<N_NODES / 4, 256, 0, stream>>>(
        node, xs, ssh, ss, ln_n_g, ln_n_b, (float*)d_out);
}

// Round 5
// 245.217 us; speedup vs baseline: 1.6047x; 1.1867x over previous
//
#include <hip/hip_runtime.h>
#include <hip/hip_bf16.h>

#define N_NODES 10000
#define N_EDGES 320000
#define D 128
#define NBINS 10000

typedef float f32x4 __attribute__((ext_vector_type(4)));
typedef float f32x2 __attribute__((ext_vector_type(2)));
typedef short bf16x8 __attribute__((ext_vector_type(8)));

static __device__ inline short f2bf(float f) {
    union { __hip_bfloat16 h; short s; } u;
    u.h = __float2bfloat16(f);
    return u.s;
}

static __device__ inline float bf2f(short s) {
    union { float f; unsigned u; } x;
    x.u = ((unsigned)(unsigned short)s) << 16;
    return x.f;
}

static __device__ inline float fast_rcp(float x) { return __builtin_amdgcn_rcpf(x); }

// All 5 weight packs in one launch.
// Region layout (shorts): [0,32768) Wsrc (K=256: W_sg;W_tp), then 4x16384 for dg,du,su,eg.
__global__ void prepack_all(const float* __restrict__ W_sg, const float* __restrict__ W_tp,
                            const float* __restrict__ W_dg, const float* __restrict__ W_du,
                            const float* __restrict__ W_su, const float* __restrict__ W_eg,
                            short* __restrict__ Wsrc, short* __restrict__ Wdg,
                            short* __restrict__ Wdu, short* __restrict__ Wsu,
                            short* __restrict__ Weg) {
    int idx = blockIdx.x * 256 + threadIdx.x;
    const float* W0; const float* W1; short* out; int i2;
    if (idx < 32768)      { W0 = W_sg; W1 = W_tp; out = Wsrc; i2 = idx; }
    else if (idx < 49152) { W0 = W_dg; W1 = W_dg; out = Wdg;  i2 = idx - 32768; }
    else if (idx < 65536) { W0 = W_du; W1 = W_du; out = Wdu;  i2 = idx - 49152; }
    else if (idx < 81920) { W0 = W_su; W1 = W_su; out = Wsu;  i2 = idx - 65536; }
    else                  { W0 = W_eg; W1 = W_eg; out = Weg;  i2 = idx - 81920; }
    int b  = i2 & 7;
    int l  = (i2 >> 3) & 63;
    int jt = (i2 >> 9) & 7;
    int t  = i2 >> 12;
    int k = 32 * t + ((l >> 4) * 8) + b;
    int j = jt * 16 + (l & 15);
    float v = (k < 128) ? W0[k * 128 + j] : W1[(k - 128) * 128 + j];
    out[i2] = f2bf(v);
}

// ---- counting sort of edges by dst ----
__global__ void hist_kernel(const int* __restrict__ dst, int* __restrict__ cnt) {
    int i = blockIdx.x * 256 + threadIdx.x;
    if (i < N_EDGES) atomicAdd(&cnt[dst[i]], 1);
}

__launch_bounds__(1024)
__global__ void scan_kernel(const int* __restrict__ cnt, int* __restrict__ cursor) {
    __shared__ int s[1024];
    int t = threadIdx.x;
    int b0 = t * 10;
    int loc[10];
    int tot = 0;
#pragma unroll
    for (int i = 0; i < 10; ++i) {
        int v = (b0 + i < NBINS) ? cnt[b0 + i] : 0;
        loc[i] = tot; tot += v;
    }
    s[t] = tot;
    __syncthreads();
    for (int off = 1; off < 1024; off <<= 1) {
        int v = (t >= off) ? s[t - off] : 0;
        __syncthreads();
        s[t] += v;
        __syncthreads();
    }
    int base = (t == 0) ? 0 : s[t - 1];
#pragma unroll
    for (int i = 0; i < 10; ++i)
        if (b0 + i < NBINS) cursor[b0 + i] = base + loc[i];
}

__global__ void scatter_kernel(const int* __restrict__ src, const int* __restrict__ dst,
                               int* __restrict__ cursor,
                               int* __restrict__ perm,
                               int* __restrict__ src_s, int* __restrict__ dst_s) {
    int i = blockIdx.x * 256 + threadIdx.x;
    if (i < N_EDGES) {
        int d = dst[i];
        int p = atomicAdd(&cursor[d], 1);
        perm[p] = i;
        src_s[p] = src[i];
        dst_s[p] = d;
    }
}

__launch_bounds__(256)
__global__ void node_proj_kernel(const float* __restrict__ node,
                                 const float* __restrict__ timef,
                                 const short* __restrict__ Wsrc_pk,  // K=256 (W_sg ; W_tp)
                                 const short* __restrict__ Wdg_pk,
                                 const short* __restrict__ Wdu_pk,
                                 const short* __restrict__ Wsu_pk,
                                 const float* __restrict__ b_sg, const float* __restrict__ b_tp,
                                 const float* __restrict__ b_dg, const float* __restrict__ b_du,
                                 const float* __restrict__ b_su, const float* __restrict__ b_eg,
                                 short* __restrict__ spk,   // [N][256] bf16, col-permuted: e_src | Bh
                                 short* __restrict__ dpk,   // [N][128] bf16, col-permuted: e_dst
                                 float* __restrict__ xs) {
    int tid = threadIdx.x;
    int w = tid >> 6;
    int l = tid & 63;
    int g = l >> 4;
    int lr = l & 15;
    int r0 = blockIdx.x * 64 + w * 16;
    int arow = r0 + lr;

    bf16x8 aN[4], aT[4];
    if (arow < N_NODES) {
        const float* np = node + (size_t)arow * D;
        const float* tp = timef + (size_t)arow * D;
#pragma unroll
        for (int t = 0; t < 4; ++t) {
            int k0 = 32 * t + g * 8;
            f32x4 v0 = *(const f32x4*)(np + k0);
            f32x4 v1 = *(const f32x4*)(np + k0 + 4);
            f32x4 u0 = *(const f32x4*)(tp + k0);
            f32x4 u1 = *(const f32x4*)(tp + k0 + 4);
            bf16x8 a, b;
#pragma unroll
            for (int i = 0; i < 4; ++i) {
                a[i] = f2bf(v0[i]); a[4 + i] = f2bf(v1[i]);
                b[i] = f2bf(u0[i]); b[4 + i] = f2bf(u1[i]);
            }
            aN[t] = a; aT[t] = b;
        }
    } else {
        bf16x8 z = {0, 0, 0, 0, 0, 0, 0, 0};
#pragma unroll
        for (int t = 0; t < 4; ++t) { aN[t] = z; aT[t] = z; }
    }

    const bf16x8* Bsrc = (const bf16x8*)Wsrc_pk;
    const bf16x8* Bdg  = (const bf16x8*)Wdg_pk;
    const bf16x8* Bdu  = (const bf16x8*)Wdu_pk;
    const bf16x8* Bsu  = (const bf16x8*)Wsu_pk;

    // e_src = node@W_sg + time@W_tp + biases   (K = 256) -> spk[:,0:128] permuted
    {
        bf16x8 chunk[4];
#pragma unroll
        for (int jt = 0; jt < 8; ++jt) {
            int c = jt * 16 + lr;
            f32x4 acc = {0.f, 0.f, 0.f, 0.f};
#pragma unroll
            for (int t = 0; t < 4; ++t)
                acc = __builtin_amdgcn_mfma_f32_16x16x32_bf16(aN[t], Bsrc[(t * 8 + jt) * 64 + l], acc, 0, 0, 0);
#pragma unroll
            for (int t = 0; t < 4; ++t)
                acc = __builtin_amdgcn_mfma_f32_16x16x32_bf16(aT[t], Bsrc[((4 + t) * 8 + jt) * 64 + l], acc, 0, 0, 0);
            float bias = b_sg[c] + b_tp[c];
#pragma unroll
            for (int r = 0; r < 4; ++r) chunk[r][jt] = f2bf(acc[r] + bias);
        }
#pragma unroll
        for (int r = 0; r < 4; ++r) {
            int row = r0 + g * 4 + r;
            if (row < N_NODES) *(bf16x8*)(spk + (size_t)row * 256 + lr * 8) = chunk[r];
        }
    }

    // e_dst (+b_dg+b_eg) -> dpk ; Bh (+b_du) -> spk[:,128:256] ; xs (+b_su) f32 plain
    {
        bf16x8 chD[4], chH[4];
        float xsv[4][8];
#pragma unroll
        for (int jt = 0; jt < 8; ++jt) {
            int c = jt * 16 + lr;
            f32x4 a0 = {0.f, 0.f, 0.f, 0.f}, a1 = a0, a2 = a0;
#pragma unroll
            for (int t = 0; t < 4; ++t) {
                a0 = __builtin_amdgcn_mfma_f32_16x16x32_bf16(aN[t], Bdg[(t * 8 + jt) * 64 + l], a0, 0, 0, 0);
                a1 = __builtin_amdgcn_mfma_f32_16x16x32_bf16(aN[t], Bdu[(t * 8 + jt) * 64 + l], a1, 0, 0, 0);
                a2 = __builtin_amdgcn_mfma_f32_16x16x32_bf16(aN[t], Bsu[(t * 8 + jt) * 64 + l], a2, 0, 0, 0);
            }
            float bdgc = b_dg[c] + b_eg[c];
            float bdu = b_du[c], bsu = b_su[c];
#pragma unroll
            for (int r = 0; r < 4; ++r) {
                chD[r][jt] = f2bf(a0[r] + bdgc);
                chH[r][jt] = f2bf(a1[r] + bdu);
                xsv[r][jt] = a2[r] + bsu;
            }
        }
#pragma unroll
        for (int r = 0; r < 4; ++r) {
            int row = r0 + g * 4 + r;
            if (row < N_NODES) {
                *(bf16x8*)(dpk + (size_t)row * D + lr * 8) = chD[r];
                *(bf16x8*)(spk + (size_t)row * 256 + 128 + lr * 8) = chH[r];
#pragma unroll
                for (int jt = 0; jt < 8; ++jt)
                    xs[(size_t)row * D + jt * 16 + lr] = xsv[r][jt];
            }
        }
    }
}

// One 16-edge tile per wave, edges in dst-sorted (perm) order. Weg staged in LDS.
// Tables are column-permuted: lane lr's 8 jt-columns of a row = one bf16x8.
__launch_bounds__(256)
__global__ void edge_kernel(const float* __restrict__ edgef,
                            const int* __restrict__ perm,
                            const int* __restrict__ src_s, const int* __restrict__ dst_s,
                            const short* __restrict__ Weg_pk,
                            const short* __restrict__ spk,   // [N][256]: e_src | Bh
                            const short* __restrict__ dpk,   // [N][128]: e_dst
                            const float* __restrict__ ln_g, const float* __restrict__ ln_b,
                            float* __restrict__ ss, float* __restrict__ ssh,
                            float* __restrict__ y) {
    __shared__ short Bs[128 * 128];  // 32 KB: Weg B-fragments
    {
        const bf16x8* gw = (const bf16x8*)Weg_pk;
        bf16x8* sw = (bf16x8*)Bs;
        for (int i = threadIdx.x; i < 2048; i += 256) sw[i] = gw[i];
    }
    __syncthreads();

    int tid = threadIdx.x;
    int w = tid >> 6;
    int l = tid & 63;
    int g = l >> 4;
    int lr = l & 15;
    // XCD-chunked bijective swizzle (5000 % 8 == 0): consecutive dst-runs on one XCD
    int b = blockIdx.x;
    int swz = (b & 7) * 625 + (b >> 3);
    int e0 = swz * 64 + w * 16;

    int eA = perm[e0 + lr];          // A-fragment row (edge) for this lane
    int eidx[4], sidx[4], didx[4];
#pragma unroll
    for (int r = 0; r < 4; ++r) {
        eidx[r] = perm[e0 + g * 4 + r];
        sidx[r] = src_s[e0 + g * 4 + r];
        didx[r] = dst_s[e0 + g * 4 + r];
    }

    // vectorized gathers: one bf16x8 per (row, table)
    bf16x8 esv[4], bhv[4], edv[4];
#pragma unroll
    for (int r = 0; r < 4; ++r) {
        esv[r] = *(const bf16x8*)(spk + (size_t)sidx[r] * 256 + lr * 8);
        bhv[r] = *(const bf16x8*)(spk + (size_t)sidx[r] * 256 + 128 + lr * 8);
        edv[r] = *(const bf16x8*)(dpk + (size_t)didx[r] * D + lr * 8);
    }

    // A fragments: 16 edges x 128 k, bf16
    bf16x8 aE[4];
    {
        const float* ep = edgef + (size_t)eA * D;
#pragma unroll
        for (int t = 0; t < 4; ++t) {
            int k0 = 32 * t + g * 8;
            f32x4 v0 = *(const f32x4*)(ep + k0);
            f32x4 v1 = *(const f32x4*)(ep + k0 + 4);
            bf16x8 a;
#pragma unroll
            for (int i = 0; i < 4; ++i) { a[i] = f2bf(v0[i]); a[4 + i] = f2bf(v1[i]); }
            aE[t] = a;
        }
    }

    const bf16x8* Bp = (const bf16x8*)Bs;
    f32x4 acc[8];
#pragma unroll
    for (int jt = 0; jt < 8; ++jt) {
        f32x4 c4 = {0.f, 0.f, 0.f, 0.f};
#pragma unroll
        for (int t = 0; t < 4; ++t)
            c4 = __builtin_amdgcn_mfma_f32_16x16x32_bf16(aE[t], Bp[(t * 8 + jt) * 64 + l], c4, 0, 0, 0);
        acc[jt] = c4;
    }

    // sorted => tile uniform iff first and last edge share dst
    int dfirst = __shfl(didx[0], 0);
    int dlast  = __shfl(didx[3], 48);
    bool uniform = (dfirst == dlast);

    float sum[4] = {0.f, 0.f, 0.f, 0.f}, sq[4] = {0.f, 0.f, 0.f, 0.f};
#pragma unroll
    for (int jt = 0; jt < 8; ++jt) {
        int c = jt * 16 + lr;
        float sg[4], bsg[4];
#pragma unroll
        for (int r = 0; r < 4; ++r) {
            float m = acc[jt][r] + bf2f(esv[r][jt]) + bf2f(edv[r][jt]);
            acc[jt][r] = m;  // keep for LN pass
            float s = fast_rcp(1.f + __expf(-m));
            sg[r] = s;
            bsg[r] = bf2f(bhv[r][jt]) * s;
            sum[r] += m; sq[r] += m * m;
        }
        if (uniform) {
            float aS = (sg[0] + sg[1]) + (sg[2] + sg[3]);
            float aH = (bsg[0] + bsg[1]) + (bsg[2] + bsg[3]);
            aS += __shfl_xor(aS, 16); aH += __shfl_xor(aH, 16);
            aS += __shfl_xor(aS, 32); aH += __shfl_xor(aH, 32);
            if (g == 0) {
                atomicAdd(&ss [(size_t)dfirst * D + c], aS);
                atomicAdd(&ssh[(size_t)dfirst * D + c], aH);
            }
        } else {
            float aS = sg[0], aH = bsg[0];
#pragma unroll
            for (int r = 1; r < 4; ++r) {
                if (didx[r] == didx[r - 1]) { aS += sg[r]; aH += bsg[r]; }
                else {
                    atomicAdd(&ss [(size_t)didx[r - 1] * D + c], aS);
                    atomicAdd(&ssh[(size_t)didx[r - 1] * D + c], aH);
                    aS = sg[r]; aH = bsg[r];
                }
            }
            atomicAdd(&ss [(size_t)didx[3] * D + c], aS);
            atomicAdd(&ssh[(size_t)didx[3] * D + c], aH);
        }
    }

    // LayerNorm stats per edge: reduce over the 16 lanes sharing l>>4
#pragma unroll
    for (int r = 0; r < 4; ++r) {
        float s = sum[r], q = sq[r];
#pragma unroll
        for (int mk = 1; mk < 16; mk <<= 1) { s += __shfl_xor(s, mk); q += __shfl_xor(q, mk); }
        float mean = s * (1.f / D);
        float var = q * (1.f / D) - mean * mean;
        sum[r] = mean;
        sq[r] = rsqrtf(var + 1e-5f);
    }

#pragma unroll
    for (int jt = 0; jt < 8; ++jt) {
        int c = jt * 16 + lr;
        float gc = ln_g[c], bc = ln_b[c];
#pragma unroll
        for (int r = 0; r < 4; ++r) {
            float v = (acc[jt][r] - sum[r]) * sq[r] * gc + bc;
            float sl = v * fast_rcp(1.f + __expf(-v));
            size_t off = (size_t)eidx[r] * D + c;
            __builtin_nontemporal_store(edgef[off] + sl, &y[off]);
        }
    }
}

__launch_bounds__(256)
__global__ void node_out_kernel(const float* __restrict__ node,
                                const float* __restrict__ xs,
                                const float* __restrict__ ssh, const float* __restrict__ ss,
                                const float* __restrict__ ln_g, const float* __restrict__ ln_b,
                                float* __restrict__ x) {
    int w = threadIdx.x >> 6;
    int l = threadIdx.x & 63;
    int row = blockIdx.x * 4 + w;
    if (row >= N_NODES) return;
    size_t base = (size_t)row * D + 2 * l;
    f32x2 xv = *(const f32x2*)(xs + base);
    f32x2 hs = *(const f32x2*)(ssh + base);
    f32x2 sv = *(const f32x2*)(ss + base);
    float v0 = xv[0] + hs[0] / (sv[0] + 1e-6f);
    float v1 = xv[1] + hs[1] / (sv[1] + 1e-6f);
    float s = v0 + v1, q = v0 * v0 + v1 * v1;
#pragma unroll
    for (int mk = 1; mk < 64; mk <<= 1) { s += __shfl_xor(s, mk); q += __shfl_xor(q, mk); }
    float mean = s * (1.f / D);
    float var = q * (1.f / D) - mean * mean;
    float rstd = rsqrtf(var + 1e-5f);
    float t0 = (v0 - mean) * rstd * ln_g[2 * l] + ln_b[2 * l];
    float t1 = (v1 - mean) * rstd * ln_g[2 * l + 1] + ln_b[2 * l + 1];
    t0 = t0 * fast_rcp(1.f + __expf(-t0));
    t1 = t1 * fast_rcp(1.f + __expf(-t1));
    f32x2 nv = *(const f32x2*)(node + base);
    f32x2 outv;
    outv[0] = nv[0] + t0;
    outv[1] = nv[1] + t1;
    *(f32x2*)(x + base) = outv;
}

extern "C" void kernel_launch(void* const* d_in, const int* in_sizes, int n_in,
                              void* d_out, int out_size, void* d_ws, size_t ws_size,
                              hipStream_t stream) {
    const float* node  = (const float*)d_in[0];
    const float* edgef = (const float*)d_in[1];
    const float* timef = (const float*)d_in[2];
    const int*   src   = (const int*)d_in[3];
    const int*   dst   = (const int*)d_in[4];
    const float* W_tp = (const float*)d_in[5];  const float* b_tp = (const float*)d_in[6];
    const float* W_sg = (const float*)d_in[7];  const float* b_sg = (const float*)d_in[8];
    const float* W_dg = (const float*)d_in[9];  const float* b_dg = (const float*)d_in[10];
    const float* W_eg = (const float*)d_in[11]; const float* b_eg = (const float*)d_in[12];
    const float* W_su = (const float*)d_in[13]; const float* b_su = (const float*)d_in[14];
    const float* W_du = (const float*)d_in[15]; const float* b_du = (const float*)d_in[16];
    const float* ln_e_g = (const float*)d_in[17]; const float* ln_e_b = (const float*)d_in[18];
    const float* ln_n_g = (const float*)d_in[19]; const float* ln_n_b = (const float*)d_in[20];

    char* ws = (char*)d_ws;
    size_t nd = (size_t)N_NODES * D;
    float* ss    = (float*)ws; ws += nd * 4;
    float* ssh   = (float*)ws; ws += nd * 4;
    float* xs    = (float*)ws; ws += nd * 4;
    short* spk   = (short*)ws; ws += (size_t)N_NODES * 256 * 2;
    short* dpk   = (short*)ws; ws += nd * 2;
    short* Wsrc_pk = (short*)ws; ws += 256 * 128 * 2;
    short* Wdg_pk  = (short*)ws; ws += 128 * 128 * 2;
    short* Wdu_pk  = (short*)ws; ws += 128 * 128 * 2;
    short* Wsu_pk  = (short*)ws; ws += 128 * 128 * 2;
    short* Weg_pk  = (short*)ws; ws += 128 * 128 * 2;
    int* cnt       = (int*)ws; ws += 10240 * 4;
    int* cursor    = (int*)ws; ws += 10240 * 4;
    int* perm      = (int*)ws; ws += (size_t)N_EDGES * 4;
    int* src_s     = (int*)ws; ws += (size_t)N_EDGES * 4;
    int* dst_s     = (int*)ws; ws += (size_t)N_EDGES * 4;

    // zero accumulators (ss & ssh contiguous) and histogram
    hipMemsetAsync(ss, 0, 2 * nd * 4, stream);
    hipMemsetAsync(cnt, 0, 10240 * 4, stream);

    // build dst-sorted edge permutation (+ pre-gathered src/dst)
    hist_kernel<<<(N_EDGES + 255) / 256, 256, 0, stream>>>(dst, cnt);
    scan_kernel<<<1, 1024, 0, stream>>>(cnt, cursor);
    scatter_kernel<<<(N_EDGES + 255) / 256, 256, 0, stream>>>(src, dst, cursor, perm, src_s, dst_s);

    prepack_all<<<384, 256, 0, stream>>>(W_sg, W_tp, W_dg, W_du, W_su, W_eg,
                                         Wsrc_pk, Wdg_pk, Wdu_pk, Wsu_pk, Weg_pk);

    node_proj_kernel<<<(N_NODES + 63) / 64, 256, 0, stream>>>(
        node, timef, Wsrc_pk, Wdg_pk, Wdu_pk, Wsu_pk,
        b_sg, b_tp, b_dg, b_du, b_su, b_eg, spk, dpk, xs);

    edge_kernel<<<N_EDGES / 64, 256, 0, stream>>>(
        edgef, perm, src_s, dst_s, Weg_pk, spk, dpk,
        ln_e_g, ln_e_b, ss, ssh, (float*)d_out + nd);

    node_out_kernel<<<N_NODES / 4, 256, 0, stream>>>(
        node, xs, ssh, ss, ln_n_g, ln_n_b, (float*)d_out);
}